// Round 9
// baseline (287.229 us; speedup 1.0000x reference)
//
#include <hip/hip_runtime.h>
#include <hip/hip_bf16.h>

// B=8, S=1024, D=1024, H=16, DH=64, N=1024, M=8192
// ws (bf16): q[8M] | k[8M] | vt[8M] | wt_q[1M] | wt_k[1M] | wt_v[1M]

typedef __bf16 bf16;
typedef unsigned int uint;
typedef float f32x4 __attribute__((ext_vector_type(4)));
typedef float f32x16 __attribute__((ext_vector_type(16)));
typedef bf16 bf16x8 __attribute__((ext_vector_type(8)));

#define QK_SCALE 0.18033688011112042f  // 0.125 * log2(e): softmax in base-2 domain

static __device__ __forceinline__ f32x4 mfma16(bf16x8 a, bf16x8 b, f32x4 c) {
    return __builtin_amdgcn_mfma_f32_16x16x32_bf16(a, b, c, 0, 0, 0);
}
static __device__ __forceinline__ f32x16 mfma32(bf16x8 a, bf16x8 b, f32x16 c) {
    return __builtin_amdgcn_mfma_f32_32x32x16_bf16(a, b, c, 0, 0, 0);
}

// ---------------- weight transpose+convert: W[k][n] f32 -> Wt[n][k] bf16 -----
// z==0 (Wq) additionally pre-scales by 0.125*log2e so softmax runs in exp2 domain.
__global__ __launch_bounds__(256)
void wconv_kernel(const float* __restrict__ Wq, const float* __restrict__ Wk,
                  const float* __restrict__ Wv, bf16* __restrict__ Tq,
                  bf16* __restrict__ Tk, bf16* __restrict__ Tv) {
    const int z = blockIdx.z;
    const float* W = z == 0 ? Wq : (z == 1 ? Wk : Wv);
    bf16* Wt = z == 0 ? Tq : (z == 1 ? Tk : Tv);
    const float sc = z == 0 ? QK_SCALE : 1.0f;
    __shared__ bf16 t[32][33];
    const int tx = threadIdx.x, ty = threadIdx.y;
    const int n0 = blockIdx.x * 32, k0 = blockIdx.y * 32;
#pragma unroll
    for (int i = 0; i < 4; ++i)
        t[ty + i * 8][tx] = (bf16)(W[(size_t)(k0 + ty + i * 8) * 1024 + n0 + tx] * sc);
    __syncthreads();
#pragma unroll
    for (int i = 0; i < 4; ++i)
        Wt[(size_t)(n0 + ty + i * 8) * 1024 + k0 + tx] = t[tx][ty + i * 8];
}

// ---------------- projection GEMM: 2-phase double-buffered (T3 minimal) ------
template <int MODE>
__global__ __launch_bounds__(256)
void gemm_proj(const float* __restrict__ X, const bf16* __restrict__ Wt,
               bf16* __restrict__ out) {
    __shared__ bf16 Asub[2][128][40];
    __shared__ bf16 Bsub[2][128][40];
    const int tid = threadIdx.x;
    const int lane = tid & 63;
    const int w = tid >> 6;
    const int m0 = blockIdx.x * 128;
    const int n0 = blockIdx.y * 128;
    const int wm = (w >> 1) * 64;
    const int wn = (w & 1) * 64;
    const int lrow = lane & 15;
    const int lk8 = (lane >> 4) * 8;
    const int lr4 = (lane >> 4) * 4;

    f32x4 acc[4][4];
#pragma unroll
    for (int i = 0; i < 4; ++i)
#pragma unroll
        for (int j = 0; j < 4; ++j)
            acc[i][j] = f32x4{0.f, 0.f, 0.f, 0.f};

    const int srow = tid >> 1;
    const int skh = (tid & 1) * 16;
    const float* xg = X + (size_t)(m0 + srow) * 1024 + skh;
    const bf16* bg = Wt + (size_t)(n0 + srow) * 1024 + skh;

    {
        const float4 f0 = *(const float4*)(xg + 0);
        const float4 f1 = *(const float4*)(xg + 4);
        const float4 f2 = *(const float4*)(xg + 8);
        const float4 f3 = *(const float4*)(xg + 12);
        const bf16x8 b0 = *(const bf16x8*)(bg + 0);
        const bf16x8 b1 = *(const bf16x8*)(bg + 8);
        bf16x8 a0, a1;
        a0[0] = (bf16)f0.x; a0[1] = (bf16)f0.y; a0[2] = (bf16)f0.z; a0[3] = (bf16)f0.w;
        a0[4] = (bf16)f1.x; a0[5] = (bf16)f1.y; a0[6] = (bf16)f1.z; a0[7] = (bf16)f1.w;
        a1[0] = (bf16)f2.x; a1[1] = (bf16)f2.y; a1[2] = (bf16)f2.z; a1[3] = (bf16)f2.w;
        a1[4] = (bf16)f3.x; a1[5] = (bf16)f3.y; a1[6] = (bf16)f3.z; a1[7] = (bf16)f3.w;
        *(bf16x8*)&Asub[0][srow][skh + 0] = a0;
        *(bf16x8*)&Asub[0][srow][skh + 8] = a1;
        *(bf16x8*)&Bsub[0][srow][skh + 0] = b0;
        *(bf16x8*)&Bsub[0][srow][skh + 8] = b1;
    }
    __syncthreads();

    int cur = 0;
    for (int kt = 0; kt < 32; ++kt) {
        float4 f0, f1, f2, f3;
        bf16x8 b0, b1;
        if (kt < 31) {
            const int k0 = (kt + 1) * 32;
            f0 = *(const float4*)(xg + k0 + 0);
            f1 = *(const float4*)(xg + k0 + 4);
            f2 = *(const float4*)(xg + k0 + 8);
            f3 = *(const float4*)(xg + k0 + 12);
            b0 = *(const bf16x8*)(bg + k0 + 0);
            b1 = *(const bf16x8*)(bg + k0 + 8);
        }
        bf16x8 af[4], bfv[4];
#pragma unroll
        for (int i = 0; i < 4; ++i)
            af[i] = *(const bf16x8*)&Asub[cur][wm + i * 16 + lrow][lk8];
#pragma unroll
        for (int j = 0; j < 4; ++j)
            bfv[j] = *(const bf16x8*)&Bsub[cur][wn + j * 16 + lrow][lk8];
#pragma unroll
        for (int i = 0; i < 4; ++i)
#pragma unroll
            for (int j = 0; j < 4; ++j)
                acc[i][j] = mfma16(af[i], bfv[j], acc[i][j]);
        if (kt < 31) {
            bf16x8 a0, a1;
            a0[0] = (bf16)f0.x; a0[1] = (bf16)f0.y; a0[2] = (bf16)f0.z; a0[3] = (bf16)f0.w;
            a0[4] = (bf16)f1.x; a0[5] = (bf16)f1.y; a0[6] = (bf16)f1.z; a0[7] = (bf16)f1.w;
            a1[0] = (bf16)f2.x; a1[1] = (bf16)f2.y; a1[2] = (bf16)f2.z; a1[3] = (bf16)f2.w;
            a1[4] = (bf16)f3.x; a1[5] = (bf16)f3.y; a1[6] = (bf16)f3.z; a1[7] = (bf16)f3.w;
            *(bf16x8*)&Asub[cur ^ 1][srow][skh + 0] = a0;
            *(bf16x8*)&Asub[cur ^ 1][srow][skh + 8] = a1;
            *(bf16x8*)&Bsub[cur ^ 1][srow][skh + 0] = b0;
            *(bf16x8*)&Bsub[cur ^ 1][srow][skh + 8] = b1;
        }
        __syncthreads();
        cur ^= 1;
    }

#pragma unroll
    for (int j = 0; j < 4; ++j) {
        const int n = n0 + wn + j * 16 + lrow;
        const int h = n >> 6, dh = n & 63;
#pragma unroll
        for (int i = 0; i < 4; ++i) {
#pragma unroll
            for (int r = 0; r < 4; ++r) {
                const int m = m0 + wm + i * 16 + lr4 + r;
                const int b = m >> 10, s = m & 1023;
                const bf16 val = (bf16)acc[i][j][r];
                if (MODE == 0)
                    out[((size_t)((b * 16 + h) * 1024 + s)) * 64 + dh] = val;
                else
                    out[((size_t)((b * 16 + h) * 64 + dh)) * 1024 + s] = val;
            }
        }
    }
}

// ---------------- flash attention, swapped-QK^T 32x32, ZERO-barrier ----------
// 1 block = (bh, 128 q rows), 4 independent waves x 32 q-rows. NO K/V LDS
// staging: fragments read direct from global (L2-resident per XCD: 16 bh x
// 256 KB = 4 MB). No __syncthreads anywhere -> waves free-run, latency hidden
// by 16 waves/CU. In-register softmax (no max: scores bounded), l deferred.
__global__ __launch_bounds__(256)
void attn_kernel(const bf16* __restrict__ Q, const bf16* __restrict__ K,
                 const bf16* __restrict__ Vt, float* __restrict__ out) {
    __shared__ float Lsub[4][32];  // per-wave l transpose (no barrier needed)

    const int tid = threadIdx.x, lane = tid & 63, w = tid >> 6;
    const int l31 = lane & 31;
    const int hi = lane >> 5;
    const int lin = blockIdx.x;
    const int xcd = lin & 7;
    const int slot = lin >> 3;
    const int bh = (slot >> 3) * 8 + xcd;
    const int qt = slot & 7;
    const int q0 = qt * 128;
    const size_t base = (size_t)bh << 16;

    // Q B-fragments: lane holds q-row = w*32 + l31, d-chunk hi*8 (+16 per ds)
    bf16x8 qf[4];
    {
        const bf16* qg = Q + base + (size_t)(q0 + w * 32 + l31) * 64 + hi * 8;
#pragma unroll
        for (int ds = 0; ds < 4; ++ds) qf[ds] = *(const bf16x8*)(qg + ds * 16);
    }

    f32x16 acc_o[2];
#pragma unroll
    for (int nf = 0; nf < 2; ++nf)
#pragma unroll
        for (int r = 0; r < 16; ++r) acc_o[nf][r] = 0.f;
    float l_acc[4] = {0.f, 0.f, 0.f, 0.f};

    // direct-global fragment base pointers
    const bf16* kp0 = K + base + (size_t)l31 * 64 + hi * 8;         // keys 0-31 row
    const bf16* kp1 = kp0 + 32 * 64;                                 // keys 32-63 row
    const bf16* vp0 = Vt + base + (size_t)l31 * 1024 + hi * 8;       // dh 0-31 row
    const bf16* vp1 = vp0 + 32 * 1024;                               // dh 32-63 row

    for (int t = 0; t < 16; ++t) {
        const int s0 = t * 64;

        // QK^T swapped: S^T[key][q]; K fragments direct from global/L2
        f32x16 sa0, sa1;
#pragma unroll
        for (int r = 0; r < 16; ++r) { sa0[r] = 0.f; sa1[r] = 0.f; }
        __builtin_amdgcn_s_setprio(1);
#pragma unroll
        for (int ds = 0; ds < 4; ++ds) {
            const bf16x8 k0 = *(const bf16x8*)(kp0 + (size_t)s0 * 64 + ds * 16);
            const bf16x8 k1 = *(const bf16x8*)(kp1 + (size_t)s0 * 64 + ds * 16);
            sa0 = mfma32(k0, qf[ds], sa0);
            sa1 = mfma32(k1, qf[ds], sa1);
        }
        __builtin_amdgcn_s_setprio(0);

        // softmax: p = exp2(s) (no max), 4 parallel l chains
        float p0[16], p1[16];
#pragma unroll
        for (int r = 0; r < 16; ++r) {
            p0[r] = __builtin_amdgcn_exp2f(sa0[r]);
            p1[r] = __builtin_amdgcn_exp2f(sa1[r]);
            l_acc[r & 3] += p0[r] + p1[r];
        }

        // pack bf16 pairs: c[b] = (p[2b] lo, p[2b+1] hi)
        uint c0[8], c1[8];
#pragma unroll
        for (int bb = 0; bb < 8; ++bb) {
            union { bf16 h[2]; uint u; } u0, u1;
            u0.h[0] = (bf16)p0[2 * bb]; u0.h[1] = (bf16)p0[2 * bb + 1];
            u1.h[0] = (bf16)p1[2 * bb]; u1.h[1] = (bf16)p1[2 * bb + 1];
            c0[bb] = u0.u; c1[bb] = u1.u;
        }
        // cross-half exchange: hi=1 sends blocks {0,1,4,5}, hi=0 sends {2,3,6,7}
        constexpr int SA[4] = {0, 1, 4, 5}, SB[4] = {2, 3, 6, 7};
        uint x0[4], x1[4];
#pragma unroll
        for (int j = 0; j < 4; ++j) {
            x0[j] = __shfl_xor(hi ? c0[SA[j]] : c0[SB[j]], 32);
            x1[j] = __shfl_xor(hi ? c1[SA[j]] : c1[SB[j]], 32);
        }
        // assemble PV A-fragments (lane-verified mapping)
        bf16x8 pf00, pf01, pf10, pf11;
#pragma unroll
        for (int ks2 = 0; ks2 < 2; ++ks2) {
            union { uint u[4]; bf16x8 v; } a0, a1;
#pragma unroll
            for (int e = 0; e < 4; ++e) {
                const int xo = (e & 1) + 2 * ks2;
                const int co = (e & 1) + 4 * ks2;
                if (e < 2) {
                    a0.u[e] = hi ? x0[xo] : c0[co];
                    a1.u[e] = hi ? x1[xo] : c1[co];
                } else {
                    a0.u[e] = hi ? c0[co + 2] : x0[xo];
                    a1.u[e] = hi ? c1[co + 2] : x1[xo];
                }
            }
            if (ks2 == 0) { pf00 = a0.v; pf10 = a1.v; }
            else          { pf01 = a0.v; pf11 = a1.v; }
        }

        // PV: O[q][d] += P[q][k] @ V[k][d]; V^T rows direct from global/L2
        __builtin_amdgcn_s_setprio(1);
#pragma unroll
        for (int ks = 0; ks < 4; ++ks) {
            const bf16x8 pa = (ks == 0) ? pf00 : (ks == 1) ? pf01
                            : (ks == 2) ? pf10 : pf11;
            const bf16x8 vf0 = *(const bf16x8*)(vp0 + s0 + ks * 16);
            const bf16x8 vf1 = *(const bf16x8*)(vp1 + s0 + ks * 16);
            acc_o[0] = mfma32(pa, vf0, acc_o[0]);
            acc_o[1] = mfma32(pa, vf1, acc_o[1]);
        }
        __builtin_amdgcn_s_setprio(0);
    }

    // finalize l per q-row (one shfl), transpose via per-wave LDS (no barrier:
    // same-wave write->read, compiler inserts lgkmcnt)
    float l_part = (l_acc[0] + l_acc[1]) + (l_acc[2] + l_acc[3]);
    const float l_tot = l_part + __shfl_xor(l_part, 32);
    if (lane < 32) Lsub[w][l31] = l_tot;
    const int b = bh >> 4, hh = bh & 15;
#pragma unroll
    for (int r = 0; r < 16; ++r) {
        const int q = (r & 3) + 8 * (r >> 2) + 4 * hi;
        const float inv = 1.0f / Lsub[w][q];
        const size_t row = (size_t)(b * 1024 + q0 + w * 32 + q) * 1024 + hh * 64;
#pragma unroll
        for (int nf = 0; nf < 2; ++nf)
            out[row + nf * 32 + l31] = acc_o[nf][r] * inv;
    }
}

extern "C" void kernel_launch(void* const* d_in, const int* in_sizes, int n_in,
                              void* d_out, int out_size, void* d_ws, size_t ws_size,
                              hipStream_t stream) {
    (void)in_sizes; (void)n_in; (void)out_size; (void)ws_size;
    const float* queries = (const float*)d_in[0];
    const float* keys    = (const float*)d_in[1];
    const float* values  = (const float*)d_in[2];
    const float* Wq      = (const float*)d_in[3];
    const float* Wk      = (const float*)d_in[4];
    const float* Wv      = (const float*)d_in[5];
    float* out = (float*)d_out;

    bf16* q_ws  = (bf16*)d_ws;
    bf16* k_ws  = q_ws + (size_t)8 * 1024 * 1024;
    bf16* vt_ws = k_ws + (size_t)8 * 1024 * 1024;
    bf16* wt_q  = vt_ws + (size_t)8 * 1024 * 1024;
    bf16* wt_k  = wt_q + (size_t)1024 * 1024;
    bf16* wt_v  = wt_k + (size_t)1024 * 1024;

    wconv_kernel<<<dim3(32, 32, 3), dim3(32, 8), 0, stream>>>(
        Wq, Wk, Wv, wt_q, wt_k, wt_v);

    gemm_proj<0><<<dim3(64, 8), 256, 0, stream>>>(queries, wt_q, q_ws);
    gemm_proj<0><<<dim3(64, 8), 256, 0, stream>>>(keys,    wt_k, k_ws);
    gemm_proj<1><<<dim3(64, 8), 256, 0, stream>>>(values,  wt_v, vt_ws);

    attn_kernel<<<dim3(1024), 256, 0, stream>>>(q_ws, k_ws, vt_ws, out);
}

// Round 11
// 159.516 us; speedup vs baseline: 1.8006x; 1.8006x over previous
//
#include <hip/hip_runtime.h>
#include <hip/hip_bf16.h>

// B=8, S=1024, D=1024, H=16, DH=64, N=1024, M=8192
// ws (bf16): q[8M] | k[8M] | vt[8M] | wt_q[1M] | wt_k[1M] | wt_v[1M]

typedef __bf16 bf16;
typedef unsigned int uint;
typedef float f32x4 __attribute__((ext_vector_type(4)));
typedef float f32x16 __attribute__((ext_vector_type(16)));
typedef bf16 bf16x8 __attribute__((ext_vector_type(8)));

#define QK_SCALE 0.18033688011112042f  // 0.125 * log2(e): softmax in base-2 domain

static __device__ __forceinline__ f32x4 mfma16(bf16x8 a, bf16x8 b, f32x4 c) {
    return __builtin_amdgcn_mfma_f32_16x16x32_bf16(a, b, c, 0, 0, 0);
}
static __device__ __forceinline__ f32x16 mfma32(bf16x8 a, bf16x8 b, f32x16 c) {
    return __builtin_amdgcn_mfma_f32_32x32x16_bf16(a, b, c, 0, 0, 0);
}

// ---------------- weight transpose+convert: W[k][n] f32 -> Wt[n][k] bf16 -----
// z==0 (Wq) additionally pre-scales by 0.125*log2e so softmax runs in exp2 domain.
__global__ __launch_bounds__(256)
void wconv_kernel(const float* __restrict__ Wq, const float* __restrict__ Wk,
                  const float* __restrict__ Wv, bf16* __restrict__ Tq,
                  bf16* __restrict__ Tk, bf16* __restrict__ Tv) {
    const int z = blockIdx.z;
    const float* W = z == 0 ? Wq : (z == 1 ? Wk : Wv);
    bf16* Wt = z == 0 ? Tq : (z == 1 ? Tk : Tv);
    const float sc = z == 0 ? QK_SCALE : 1.0f;
    __shared__ bf16 t[32][33];
    const int tx = threadIdx.x, ty = threadIdx.y;
    const int n0 = blockIdx.x * 32, k0 = blockIdx.y * 32;
#pragma unroll
    for (int i = 0; i < 4; ++i)
        t[ty + i * 8][tx] = (bf16)(W[(size_t)(k0 + ty + i * 8) * 1024 + n0 + tx] * sc);
    __syncthreads();
#pragma unroll
    for (int i = 0; i < 4; ++i)
        Wt[(size_t)(n0 + ty + i * 8) * 1024 + k0 + tx] = t[tx][ty + i * 8];
}

// ---------------- projection GEMM: 2-phase double-buffered (T3 minimal) ------
template <int MODE>
__global__ __launch_bounds__(256)
void gemm_proj(const float* __restrict__ X, const bf16* __restrict__ Wt,
               bf16* __restrict__ out) {
    __shared__ bf16 Asub[2][128][40];
    __shared__ bf16 Bsub[2][128][40];
    const int tid = threadIdx.x;
    const int lane = tid & 63;
    const int w = tid >> 6;
    const int m0 = blockIdx.x * 128;
    const int n0 = blockIdx.y * 128;
    const int wm = (w >> 1) * 64;
    const int wn = (w & 1) * 64;
    const int lrow = lane & 15;
    const int lk8 = (lane >> 4) * 8;
    const int lr4 = (lane >> 4) * 4;

    f32x4 acc[4][4];
#pragma unroll
    for (int i = 0; i < 4; ++i)
#pragma unroll
        for (int j = 0; j < 4; ++j)
            acc[i][j] = f32x4{0.f, 0.f, 0.f, 0.f};

    const int srow = tid >> 1;
    const int skh = (tid & 1) * 16;
    const float* xg = X + (size_t)(m0 + srow) * 1024 + skh;
    const bf16* bg = Wt + (size_t)(n0 + srow) * 1024 + skh;

    {
        const float4 f0 = *(const float4*)(xg + 0);
        const float4 f1 = *(const float4*)(xg + 4);
        const float4 f2 = *(const float4*)(xg + 8);
        const float4 f3 = *(const float4*)(xg + 12);
        const bf16x8 b0 = *(const bf16x8*)(bg + 0);
        const bf16x8 b1 = *(const bf16x8*)(bg + 8);
        bf16x8 a0, a1;
        a0[0] = (bf16)f0.x; a0[1] = (bf16)f0.y; a0[2] = (bf16)f0.z; a0[3] = (bf16)f0.w;
        a0[4] = (bf16)f1.x; a0[5] = (bf16)f1.y; a0[6] = (bf16)f1.z; a0[7] = (bf16)f1.w;
        a1[0] = (bf16)f2.x; a1[1] = (bf16)f2.y; a1[2] = (bf16)f2.z; a1[3] = (bf16)f2.w;
        a1[4] = (bf16)f3.x; a1[5] = (bf16)f3.y; a1[6] = (bf16)f3.z; a1[7] = (bf16)f3.w;
        *(bf16x8*)&Asub[0][srow][skh + 0] = a0;
        *(bf16x8*)&Asub[0][srow][skh + 8] = a1;
        *(bf16x8*)&Bsub[0][srow][skh + 0] = b0;
        *(bf16x8*)&Bsub[0][srow][skh + 8] = b1;
    }
    __syncthreads();

    int cur = 0;
    for (int kt = 0; kt < 32; ++kt) {
        float4 f0, f1, f2, f3;
        bf16x8 b0, b1;
        if (kt < 31) {
            const int k0 = (kt + 1) * 32;
            f0 = *(const float4*)(xg + k0 + 0);
            f1 = *(const float4*)(xg + k0 + 4);
            f2 = *(const float4*)(xg + k0 + 8);
            f3 = *(const float4*)(xg + k0 + 12);
            b0 = *(const bf16x8*)(bg + k0 + 0);
            b1 = *(const bf16x8*)(bg + k0 + 8);
        }
        bf16x8 af[4], bfv[4];
#pragma unroll
        for (int i = 0; i < 4; ++i)
            af[i] = *(const bf16x8*)&Asub[cur][wm + i * 16 + lrow][lk8];
#pragma unroll
        for (int j = 0; j < 4; ++j)
            bfv[j] = *(const bf16x8*)&Bsub[cur][wn + j * 16 + lrow][lk8];
#pragma unroll
        for (int i = 0; i < 4; ++i)
#pragma unroll
            for (int j = 0; j < 4; ++j)
                acc[i][j] = mfma16(af[i], bfv[j], acc[i][j]);
        if (kt < 31) {
            bf16x8 a0, a1;
            a0[0] = (bf16)f0.x; a0[1] = (bf16)f0.y; a0[2] = (bf16)f0.z; a0[3] = (bf16)f0.w;
            a0[4] = (bf16)f1.x; a0[5] = (bf16)f1.y; a0[6] = (bf16)f1.z; a0[7] = (bf16)f1.w;
            a1[0] = (bf16)f2.x; a1[1] = (bf16)f2.y; a1[2] = (bf16)f2.z; a1[3] = (bf16)f2.w;
            a1[4] = (bf16)f3.x; a1[5] = (bf16)f3.y; a1[6] = (bf16)f3.z; a1[7] = (bf16)f3.w;
            *(bf16x8*)&Asub[cur ^ 1][srow][skh + 0] = a0;
            *(bf16x8*)&Asub[cur ^ 1][srow][skh + 8] = a1;
            *(bf16x8*)&Bsub[cur ^ 1][srow][skh + 0] = b0;
            *(bf16x8*)&Bsub[cur ^ 1][srow][skh + 8] = b1;
        }
        __syncthreads();
        cur ^= 1;
    }

#pragma unroll
    for (int j = 0; j < 4; ++j) {
        const int n = n0 + wn + j * 16 + lrow;
        const int h = n >> 6, dh = n & 63;
#pragma unroll
        for (int i = 0; i < 4; ++i) {
#pragma unroll
            for (int r = 0; r < 4; ++r) {
                const int m = m0 + wm + i * 16 + lr4 + r;
                const int b = m >> 10, s = m & 1023;
                const bf16 val = (bf16)acc[i][j][r];
                if (MODE == 0)
                    out[((size_t)((b * 16 + h) * 1024 + s)) * 64 + dh] = val;
                else
                    out[((size_t)((b * 16 + h) * 64 + dh)) * 1024 + s] = val;
            }
        }
    }
}

// ---------------- flash attention, swapped-QK^T 32x32, 2-phase dbuf ----------
// R8 structure (measured 92 us) + CORRECTED permlane32_swap exchange (T12).
// gfx950 semantics: v_permlane32_swap_b32 vdst, vsrc exchanges
//   vdst[lanes 32:63] <-> vsrc[lanes 0:31]   (vdst-high <-> vsrc-low).
// With vdst=c[SA], vsrc=c[SB]:
//   new_vdst[l>=32] = partner's c[SB]  (what hi lanes need)
//   new_vsrc[l<32]  = partner's c[SA]  (what lo lanes need)
// so x = hi ? vdst : vsrc  ==  __shfl_xor(hi ? c[SA] : c[SB], 32).
__global__ __launch_bounds__(256)
void attn_kernel(const bf16* __restrict__ Q, const bf16* __restrict__ K,
                 const bf16* __restrict__ Vt, float* __restrict__ out) {
    __shared__ bf16 Ksub[2][64][72];   // 2 x 64 keys x 64 dh (+8 pad)
    __shared__ bf16 Vsub[2][64][72];   // 2 x 64 dh x 64 keys (V^T)
    __shared__ float Lsub[4][32];

    const int tid = threadIdx.x, lane = tid & 63, w = tid >> 6;
    const int l31 = lane & 31;
    const int hi = lane >> 5;
    const int lin = blockIdx.x;
    const int xcd = lin & 7;
    const int slot = lin >> 3;
    const int bh = (slot >> 3) * 8 + xcd;
    const int qt = slot & 7;
    const int q0 = qt * 128;
    const size_t base = (size_t)bh << 16;

    bf16x8 qf[4];
    {
        const bf16* qg = Q + base + (size_t)(q0 + w * 32 + l31) * 64 + hi * 8;
#pragma unroll
        for (int ds = 0; ds < 4; ++ds) qf[ds] = *(const bf16x8*)(qg + ds * 16);
    }

    f32x16 acc_o[2];
#pragma unroll
    for (int nf = 0; nf < 2; ++nf)
#pragma unroll
        for (int r = 0; r < 16; ++r) acc_o[nf][r] = 0.f;
    float l_acc[4] = {0.f, 0.f, 0.f, 0.f};

    const bf16* kg = K + base + (size_t)(tid >> 2) * 64 + (tid & 3) * 16;
    const bf16* vg = Vt + base + (size_t)(tid >> 2) * 1024 + (tid & 3) * 16;

    // prologue: tile 0 -> buf 0
    {
        const bf16x8 kv0 = *(const bf16x8*)(kg + 0);
        const bf16x8 kv1 = *(const bf16x8*)(kg + 8);
        const bf16x8 vv0 = *(const bf16x8*)(vg + 0);
        const bf16x8 vv1 = *(const bf16x8*)(vg + 8);
        bf16* kd = &Ksub[0][tid >> 2][(tid & 3) * 16];
        bf16* vd = &Vsub[0][tid >> 2][(tid & 3) * 16];
        *(bf16x8*)(kd + 0) = kv0; *(bf16x8*)(kd + 8) = kv1;
        *(bf16x8*)(vd + 0) = vv0; *(bf16x8*)(vd + 8) = vv1;
    }
    __syncthreads();

    int cur = 0;
    for (int t = 0; t < 16; ++t) {
        // issue next tile's loads (hide under this tile's compute)
        bf16x8 kv0, kv1, vv0, vv1;
        if (t < 15) {
            const int sn = (t + 1) * 64;
            kv0 = *(const bf16x8*)(kg + sn * 64 + 0);
            kv1 = *(const bf16x8*)(kg + sn * 64 + 8);
            vv0 = *(const bf16x8*)(vg + sn + 0);
            vv1 = *(const bf16x8*)(vg + sn + 8);
        }

        // QK^T swapped: S^T[key][q]
        f32x16 sa0, sa1;
#pragma unroll
        for (int r = 0; r < 16; ++r) { sa0[r] = 0.f; sa1[r] = 0.f; }
        __builtin_amdgcn_s_setprio(1);
#pragma unroll
        for (int ds = 0; ds < 4; ++ds) {
            const bf16x8 k0 = *(const bf16x8*)&Ksub[cur][l31][ds * 16 + hi * 8];
            const bf16x8 k1 = *(const bf16x8*)&Ksub[cur][32 + l31][ds * 16 + hi * 8];
            sa0 = mfma32(k0, qf[ds], sa0);
            sa1 = mfma32(k1, qf[ds], sa1);
        }
        __builtin_amdgcn_s_setprio(0);

        // softmax: p = exp2(s) (no max: scores bounded), 4 parallel l chains
        float p0[16], p1[16];
#pragma unroll
        for (int r = 0; r < 16; ++r) {
            p0[r] = __builtin_amdgcn_exp2f(sa0[r]);
            p1[r] = __builtin_amdgcn_exp2f(sa1[r]);
            l_acc[r & 3] += p0[r] + p1[r];
        }

        // pack bf16 pairs: c[b] = (p[2b] lo, p[2b+1] hi)
        uint c0[8], c1[8];
#pragma unroll
        for (int bb = 0; bb < 8; ++bb) {
            union { bf16 h[2]; uint u; } u0, u1;
            u0.h[0] = (bf16)p0[2 * bb]; u0.h[1] = (bf16)p0[2 * bb + 1];
            u1.h[0] = (bf16)p1[2 * bb]; u1.h[1] = (bf16)p1[2 * bb + 1];
            c0[bb] = u0.u; c1[bb] = u1.u;
        }
        // cross-half exchange via v_permlane32_swap_b32 (corrected operand roles)
        constexpr int SAi[4] = {0, 1, 4, 5}, SBi[4] = {2, 3, 6, 7};
        uint x0[4], x1[4];
#pragma unroll
        for (int j = 0; j < 4; ++j) {
            uint A0 = c0[SAi[j]], B0 = c0[SBi[j]];
            asm("v_permlane32_swap_b32 %0, %1" : "+v"(A0), "+v"(B0));
            x0[j] = hi ? A0 : B0;
            uint A1 = c1[SAi[j]], B1 = c1[SBi[j]];
            asm("v_permlane32_swap_b32 %0, %1" : "+v"(A1), "+v"(B1));
            x1[j] = hi ? A1 : B1;
        }
        // assemble PV A-fragments (lane-verified mapping)
        bf16x8 pf00, pf01, pf10, pf11;
#pragma unroll
        for (int ks2 = 0; ks2 < 2; ++ks2) {
            union { uint u[4]; bf16x8 v; } a0, a1;
#pragma unroll
            for (int e = 0; e < 4; ++e) {
                const int xo = (e & 1) + 2 * ks2;
                const int co = (e & 1) + 4 * ks2;
                if (e < 2) {
                    a0.u[e] = hi ? x0[xo] : c0[co];
                    a1.u[e] = hi ? x1[xo] : c1[co];
                } else {
                    a0.u[e] = hi ? c0[co + 2] : x0[xo];
                    a1.u[e] = hi ? c1[co + 2] : x1[xo];
                }
            }
            if (ks2 == 0) { pf00 = a0.v; pf10 = a1.v; }
            else          { pf01 = a0.v; pf11 = a1.v; }
        }

        // PV: O[q][d] += P[q][k] @ V[k][d]
        __builtin_amdgcn_s_setprio(1);
#pragma unroll
        for (int ks = 0; ks < 4; ++ks) {
            const bf16x8 pa = (ks == 0) ? pf00 : (ks == 1) ? pf01
                            : (ks == 2) ? pf10 : pf11;
#pragma unroll
            for (int nf = 0; nf < 2; ++nf) {
                const bf16x8 vf =
                    *(const bf16x8*)&Vsub[cur][nf * 32 + l31][ks * 16 + hi * 8];
                acc_o[nf] = mfma32(pa, vf, acc_o[nf]);
            }
        }
        __builtin_amdgcn_s_setprio(0);

        // write next tile into the other buffer (waits on its loads only)
        if (t < 15) {
            bf16* kd = &Ksub[cur ^ 1][tid >> 2][(tid & 3) * 16];
            bf16* vd = &Vsub[cur ^ 1][tid >> 2][(tid & 3) * 16];
            *(bf16x8*)(kd + 0) = kv0; *(bf16x8*)(kd + 8) = kv1;
            *(bf16x8*)(vd + 0) = vv0; *(bf16x8*)(vd + 8) = vv1;
        }
        __syncthreads();
        cur ^= 1;
    }

    // finalize l per q-row (one shfl), transpose via per-wave LDS
    float l_part = (l_acc[0] + l_acc[1]) + (l_acc[2] + l_acc[3]);
    const float l_tot = l_part + __shfl_xor(l_part, 32);
    if (lane < 32) Lsub[w][l31] = l_tot;
    const int b = bh >> 4, hh = bh & 15;
#pragma unroll
    for (int r = 0; r < 16; ++r) {
        const int q = (r & 3) + 8 * (r >> 2) + 4 * hi;
        const float inv = 1.0f / Lsub[w][q];
        const size_t row = (size_t)(b * 1024 + q0 + w * 32 + q) * 1024 + hh * 64;
#pragma unroll
        for (int nf = 0; nf < 2; ++nf)
            out[row + nf * 32 + l31] = acc_o[nf][r] * inv;
    }
}

extern "C" void kernel_launch(void* const* d_in, const int* in_sizes, int n_in,
                              void* d_out, int out_size, void* d_ws, size_t ws_size,
                              hipStream_t stream) {
    (void)in_sizes; (void)n_in; (void)out_size; (void)ws_size;
    const float* queries = (const float*)d_in[0];
    const float* keys    = (const float*)d_in[1];
    const float* values  = (const float*)d_in[2];
    const float* Wq      = (const float*)d_in[3];
    const float* Wk      = (const float*)d_in[4];
    const float* Wv      = (const float*)d_in[5];
    float* out = (float*)d_out;

    bf16* q_ws  = (bf16*)d_ws;
    bf16* k_ws  = q_ws + (size_t)8 * 1024 * 1024;
    bf16* vt_ws = k_ws + (size_t)8 * 1024 * 1024;
    bf16* wt_q  = vt_ws + (size_t)8 * 1024 * 1024;
    bf16* wt_k  = wt_q + (size_t)1024 * 1024;
    bf16* wt_v  = wt_k + (size_t)1024 * 1024;

    wconv_kernel<<<dim3(32, 32, 3), dim3(32, 8), 0, stream>>>(
        Wq, Wk, Wv, wt_q, wt_k, wt_v);

    gemm_proj<0><<<dim3(64, 8), 256, 0, stream>>>(queries, wt_q, q_ws);
    gemm_proj<0><<<dim3(64, 8), 256, 0, stream>>>(keys,    wt_k, k_ws);
    gemm_proj<1><<<dim3(64, 8), 256, 0, stream>>>(values,  wt_v, vt_ws);

    attn_kernel<<<dim3(1024), 256, 0, stream>>>(q_ws, k_ws, vt_ws, out);
}